// Round 2
// baseline (459.702 us; speedup 1.0000x reference)
//
#include <hip/hip_runtime.h>

// TCM_77464030151162: x(N,128)@w1+b1 -> split 64/64 -> two gathered 3^3 sparse
// convs (27 offsets, 64x64 each) with ReLU -> +2*conv_x residual -> concat@w2+b2 -> +x.
// Wire dtypes: ALL inputs/outputs fp32 (reference is jnp.float32). Tolerance is
// bf16-grade (floor_eps_k=8), so compute in bf16 MFMA with fp32 accumulate.
// N=100000, C=128, H=64.

#define N_PTS 100000
#define NBLK 782 // ceil(100000/128)

typedef __attribute__((ext_vector_type(8))) short frag_ab; // 8 bf16 (4 VGPRs)
typedef __attribute__((ext_vector_type(4))) float f32x4;   // MFMA 16x16 C/D

__device__ __forceinline__ unsigned short f2bf(float f) {
  union { float f; unsigned int i; } v; v.f = f;
  unsigned int r = v.i + 0x7fffu + ((v.i >> 16) & 1u); // RNE
  return (unsigned short)(r >> 16);
}

// ---- weight convert+transpose: Wt[d][c] = bf16(W[c][d]) ----
__global__ __launch_bounds__(256) void k_prep(
    const float* __restrict__ w1, const float* __restrict__ w2,
    const float* __restrict__ rw1, const float* __restrict__ rw2,
    unsigned short* __restrict__ w1T, unsigned short* __restrict__ w2T,
    unsigned short* __restrict__ rw1T, unsigned short* __restrict__ rw2T) {
  int t = blockIdx.x * 256 + threadIdx.x;
  if (t < 128 * 128) {
    int c = t >> 7, d = t & 127;
    w1T[d * 128 + c] = f2bf(w1[t]);
    w2T[d * 128 + c] = f2bf(w2[t]);
  }
  if (t < 27 * 64 * 64) {
    int k = t >> 12, r = t & 4095, c = r >> 6, d = r & 63;
    int o = (k << 12) + d * 64 + c;
    rw1T[o] = f2bf(rw1[t]);
    rw2T[o] = f2bf(rw2[t]);
  }
}

// ---- x fp32 -> bf16 copy (vectorized) ----
__global__ __launch_bounds__(256) void k_cvt(
    const float* __restrict__ x, unsigned short* __restrict__ xb) {
  int i = (blockIdx.x * 256 + threadIdx.x) * 4;
  if (i < N_PTS * 128) {
    float4 v = *(const float4*)(x + i);
    ushort4 o;
    o.x = f2bf(v.x); o.y = f2bf(v.y); o.z = f2bf(v.z); o.w = f2bf(v.w);
    *(ushort4*)(xb + i) = o;
  }
}

// ---- y = xb @ w1 + b1  (M=100000, N=128, K=128), y bf16 ----
__global__ __launch_bounds__(256) void k_gemm_in(
    const unsigned short* __restrict__ xb, const unsigned short* __restrict__ w1T,
    const float* __restrict__ b1, unsigned short* __restrict__ y) {
  const int lane = threadIdx.x & 63;
  const int w = threadIdx.x >> 6;
  const int m16 = lane & 15, q = lane >> 4;
  const int rowbase = blockIdx.x * 128 + w * 32;
  f32x4 acc[2][8] = {};
#pragma unroll
  for (int kk = 0; kk < 4; ++kk) {
    frag_ab a[2];
#pragma unroll
    for (int rt = 0; rt < 2; ++rt) {
      int r = rowbase + rt * 16 + m16;
      int rc = r < N_PTS ? r : 0;
      a[rt] = *(const frag_ab*)(xb + (size_t)rc * 128 + kk * 32 + q * 8);
    }
#pragma unroll
    for (int ct = 0; ct < 8; ++ct) {
      frag_ab b = *(const frag_ab*)(w1T + (size_t)(ct * 16 + m16) * 128 + kk * 32 + q * 8);
      acc[0][ct] = __builtin_amdgcn_mfma_f32_16x16x32_bf16(a[0], b, acc[0][ct], 0, 0, 0);
      acc[1][ct] = __builtin_amdgcn_mfma_f32_16x16x32_bf16(a[1], b, acc[1][ct], 0, 0, 0);
    }
  }
#pragma unroll
  for (int ct = 0; ct < 8; ++ct) {
    int col = ct * 16 + m16;
    float bias = b1[col];
#pragma unroll
    for (int rt = 0; rt < 2; ++rt)
#pragma unroll
      for (int j = 0; j < 4; ++j) {
        int r = rowbase + rt * 16 + q * 4 + j;
        if (r < N_PTS) y[(size_t)r * 128 + col] = f2bf(acc[rt][ct][j] + bias);
      }
  }
}

// ---- gathered sparse conv: out[n,d] = relu(sum_k feat[nbr[k,n],:] @ rw[k] + rb)
// FUSE: out += 2*res[n,:64] (res bf16, row stride 128). out bf16 (N x 64).
template <bool FUSE>
__global__ __launch_bounds__(256) void k_conv(
    const unsigned short* __restrict__ feat, int fstride,
    const int* __restrict__ nbr,
    const unsigned short* __restrict__ rwT, const float* __restrict__ rb,
    const unsigned short* __restrict__ res, unsigned short* __restrict__ out) {
  const int lane = threadIdx.x & 63;
  const int w = threadIdx.x >> 6;
  const int m16 = lane & 15, q = lane >> 4;
  const int rowbase = blockIdx.x * 128 + w * 32;
  f32x4 acc[2][4] = {};
  for (int k = 0; k < 27; ++k) {
    int p0 = rowbase + m16;
    int p1 = rowbase + 16 + m16;
    int idx0 = (p0 < N_PTS) ? nbr[k * N_PTS + p0] : -1;
    int idx1 = (p1 < N_PTS) ? nbr[k * N_PTS + p1] : -1;
    const unsigned short* wk = rwT + (k << 12);
#pragma unroll
    for (int kk = 0; kk < 2; ++kk) {
      frag_ab a0 = {0, 0, 0, 0, 0, 0, 0, 0};
      frag_ab a1 = {0, 0, 0, 0, 0, 0, 0, 0};
      if (idx0 >= 0) a0 = *(const frag_ab*)(feat + (size_t)idx0 * fstride + kk * 32 + q * 8);
      if (idx1 >= 0) a1 = *(const frag_ab*)(feat + (size_t)idx1 * fstride + kk * 32 + q * 8);
#pragma unroll
      for (int ct = 0; ct < 4; ++ct) {
        frag_ab b = *(const frag_ab*)(wk + (ct * 16 + m16) * 64 + kk * 32 + q * 8);
        acc[0][ct] = __builtin_amdgcn_mfma_f32_16x16x32_bf16(a0, b, acc[0][ct], 0, 0, 0);
        acc[1][ct] = __builtin_amdgcn_mfma_f32_16x16x32_bf16(a1, b, acc[1][ct], 0, 0, 0);
      }
    }
  }
#pragma unroll
  for (int ct = 0; ct < 4; ++ct) {
    int col = ct * 16 + m16;
    float bias = rb[col];
#pragma unroll
    for (int rt = 0; rt < 2; ++rt)
#pragma unroll
      for (int j = 0; j < 4; ++j) {
        int r = rowbase + rt * 16 + q * 4 + j;
        if (r < N_PTS) {
          float v = acc[rt][ct][j] + bias;
          v = v > 0.f ? v : 0.f;
          if constexpr (FUSE) {
            union { unsigned int i; float f; } u;
            u.i = ((unsigned int)res[(size_t)r * 128 + col]) << 16;
            v += 2.f * u.f;
          }
          out[(size_t)r * 64 + col] = f2bf(v);
        }
      }
  }
}

// ---- out = x + [z1 | y[:,64:]] @ w2 + b2 ; out fp32, x fp32 skip ----
__global__ __launch_bounds__(256) void k_gemm_out(
    const float* __restrict__ x, const unsigned short* __restrict__ z1,
    const unsigned short* __restrict__ y, const unsigned short* __restrict__ w2T,
    const float* __restrict__ b2, float* __restrict__ out) {
  const int lane = threadIdx.x & 63;
  const int w = threadIdx.x >> 6;
  const int m16 = lane & 15, q = lane >> 4;
  const int rowbase = blockIdx.x * 128 + w * 32;
  f32x4 acc[2][8] = {};
#pragma unroll
  for (int kk = 0; kk < 4; ++kk) {
    frag_ab a[2];
#pragma unroll
    for (int rt = 0; rt < 2; ++rt) {
      int r = rowbase + rt * 16 + m16;
      int rc = r < N_PTS ? r : 0;
      const unsigned short* ap = (kk < 2)
          ? (z1 + (size_t)rc * 64 + kk * 32 + q * 8)
          : (y + (size_t)rc * 128 + 64 + (kk - 2) * 32 + q * 8);
      a[rt] = *(const frag_ab*)ap;
    }
#pragma unroll
    for (int ct = 0; ct < 8; ++ct) {
      frag_ab b = *(const frag_ab*)(w2T + (size_t)(ct * 16 + m16) * 128 + kk * 32 + q * 8);
      acc[0][ct] = __builtin_amdgcn_mfma_f32_16x16x32_bf16(a[0], b, acc[0][ct], 0, 0, 0);
      acc[1][ct] = __builtin_amdgcn_mfma_f32_16x16x32_bf16(a[1], b, acc[1][ct], 0, 0, 0);
    }
  }
#pragma unroll
  for (int ct = 0; ct < 8; ++ct) {
    int col = ct * 16 + m16;
    float bias = b2[col];
#pragma unroll
    for (int rt = 0; rt < 2; ++rt)
#pragma unroll
      for (int j = 0; j < 4; ++j) {
        int r = rowbase + rt * 16 + q * 4 + j;
        if (r < N_PTS) {
          size_t o = (size_t)r * 128 + col;
          out[o] = acc[rt][ct][j] + bias + x[o];
        }
      }
  }
}

extern "C" void kernel_launch(void* const* d_in, const int* in_sizes, int n_in,
                              void* d_out, int out_size, void* d_ws, size_t ws_size,
                              hipStream_t stream) {
  const float* x   = (const float*)d_in[0];
  const float* w1  = (const float*)d_in[1];
  const float* b1  = (const float*)d_in[2];
  const float* w2  = (const float*)d_in[3];
  const float* b2  = (const float*)d_in[4];
  const float* rw1 = (const float*)d_in[5];
  const float* rb1 = (const float*)d_in[6];
  const float* rw2 = (const float*)d_in[7];
  const float* rb2 = (const float*)d_in[8];
  const int* nbr = (const int*)d_in[9];
  float* out = (float*)d_out;

  // workspace layout (all 16B-aligned):
  char* ws = (char*)d_ws;
  unsigned short* w1T  = (unsigned short*)(ws);                       // 32 KB
  unsigned short* w2T  = (unsigned short*)(ws + 32768);               // 32 KB
  unsigned short* rw1T = (unsigned short*)(ws + 65536);               // 216 KB
  unsigned short* rw2T = (unsigned short*)(ws + 286720);              // 216 KB
  unsigned short* xb   = (unsigned short*)(ws + 507904);              // 25.6 MB
  unsigned short* y    = (unsigned short*)(ws + 507904 + 25600000);   // 25.6 MB
  unsigned short* r1   = (unsigned short*)(ws + 507904 + 51200000);   // 12.8 MB
  unsigned short* z1   = (unsigned short*)(ws + 507904 + 64000000);   // 12.8 MB

  k_prep<<<432, 256, 0, stream>>>(w1, w2, rw1, rw2, w1T, w2T, rw1T, rw2T);
  k_cvt<<<12500, 256, 0, stream>>>(x, xb);
  k_gemm_in<<<NBLK, 256, 0, stream>>>(xb, w1T, b1, y);
  k_conv<false><<<NBLK, 256, 0, stream>>>(y, 128, nbr, rw1T, rb1, nullptr, r1);
  k_conv<true><<<NBLK, 256, 0, stream>>>(r1, 64, nbr, rw2T, rb2, y, z1);
  k_gemm_out<<<NBLK, 256, 0, stream>>>(x, z1, y, w2T, b2, out);
}